// Round 6
// baseline (608.405 us; speedup 1.0000x reference)
//
#include <hip/hip_runtime.h>

typedef unsigned short u16;
typedef __attribute__((ext_vector_type(8))) short short8;
typedef __attribute__((ext_vector_type(4))) float f32x4;
typedef __attribute__((ext_vector_type(2))) float f32x2;

#define NN 16384   // nodes
#define EE 131072  // edges
#define ERO 32768  // readout edges
#define DF 1024    // appearance dim
#define DL 300     // word2vec dim
#define DLP 320    // K-padded language dim (mult of 32)
#define DLN 384    // N-padded language B^T storage rows (3 tiles of 128)
#define DS 16      // spatial dim
#define NC 117     // classes
#define NCP 128    // padded classes

__device__ __forceinline__ float bf2f(u16 x) {
  unsigned int u = ((unsigned int)x) << 16;
  float f;
  __builtin_memcpy(&f, &u, 4);
  return f;
}
__device__ __forceinline__ u16 f2bf(float f) {
  unsigned int u;
  __builtin_memcpy(&u, &f, 4);
  u = (u + 0x7FFFu + ((u >> 16) & 1u)) >> 16;
  return (u16)u;
}
__device__ __forceinline__ float ld1(const void* p, size_t i, int f) {
  return f ? ((const float*)p)[i] : bf2f(((const u16*)p)[i]);
}
__device__ __forceinline__ void ld4(const void* p, size_t i, int f,
                                    float& x, float& y, float& z, float& w) {
  if (f) {
    float4 v = *(const float4*)((const float*)p + i);
    x = v.x; y = v.y; z = v.z; w = v.w;
  } else {
    ushort4 v = *(const ushort4*)((const u16*)p + i);
    x = bf2f(v.x); y = bf2f(v.y); z = bf2f(v.z); w = bf2f(v.w);
  }
}
__device__ __forceinline__ const void* eoff(const void* p, size_t off, int f) {
  return f ? (const void*)((const float*)p + off) : (const void*)((const u16*)p + off);
}

// dtype probe (measured: f32 on this harness; kept adaptive for safety)
__global__ void detect_kernel(const unsigned int* __restrict__ w, int* __restrict__ flag) {
  unsigned int x = w[threadIdx.x];
  int e = (x >> 7) & 0xFF;
  int ok = (e >= 97 && e <= 157);
  unsigned long long m = __ballot(ok);
  if (threadIdx.x == 0) flag[0] = (__popcll(m) >= 48) ? 0 : 1;  // 0=bf16, 1=f32
}

// contiguous cast to bf16, 8 elems/thread
__global__ void cast_bf16(const int* __restrict__ flag, const void* __restrict__ src,
                          u16* __restrict__ dst, int total8) {
  const int i = blockIdx.x * 256 + threadIdx.x;
  if (i >= total8) return;
  const int fin = flag[0];
  const size_t o = (size_t)i * 8;
  float x0, x1, x2, x3, x4, x5, x6, x7;
  ld4(src, o, fin, x0, x1, x2, x3);
  ld4(src, o + 4, fin, x4, x5, x6, x7);
  ushort4 lo, hi;
  lo.x = f2bf(x0); lo.y = f2bf(x1); lo.z = f2bf(x2); lo.w = f2bf(x3);
  hi.x = f2bf(x4); hi.y = f2bf(x5); hi.z = f2bf(x6); hi.w = f2bf(x7);
  *(ushort4*)(dst + o) = lo;
  *(ushort4*)(dst + o + 4) = hi;
}

// w2v [NN][300] (f32 or bf16) -> bf16 [NN][DLP=320], zero-padded K
__global__ void cast_w2v(const int* __restrict__ flag, const void* __restrict__ src,
                         u16* __restrict__ dst) {
  const int i = blockIdx.x * 256 + threadIdx.x;  // over NN*80 groups of 4
  if (i >= NN * 80) return;
  const int fin = flag[0];
  const int n = i / 80, g = i - n * 80;
  const int c = g << 2;
  ushort4 o;
  if (c < DL) {  // 300 % 4 == 0 -> group fully real or fully pad
    const size_t base = (size_t)n * DL + c;
    o.x = f2bf(ld1(src, base + 0, fin));
    o.y = f2bf(ld1(src, base + 1, fin));
    o.z = f2bf(ld1(src, base + 2, fin));
    o.w = f2bf(ld1(src, base + 3, fin));
  } else {
    o.x = 0; o.y = 0; o.z = 0; o.w = 0;
  }
  *(ushort4*)(dst + (size_t)n * DLP + c) = o;
}

// ---- fused weight prep: 12 transposes in one launch ----
struct TJob2 {
  const void* W; long off;
  u16* out;
  int Kr, Nr, Nstr, Kp, Np, blk0;
};
struct TPack2 { TJob2 j[12]; int nj; };

__global__ void prep_weights2(const int* __restrict__ flag, TPack2 P) {
  int b = blockIdx.x;
  int ji = 0;
  while (ji + 1 < P.nj && b >= P.j[ji + 1].blk0) ++ji;
  const TJob2 J = P.j[ji];
  const int idx = (b - J.blk0) * 256 + threadIdx.x;
  if (idx >= J.Np * J.Kp) return;
  const int n = idx / J.Kp, k = idx % J.Kp;
  float v = 0.f;
  if (k < J.Kr && n < J.Nr) v = ld1(J.W, (size_t)J.off + (size_t)k * J.Nstr + n, flag[0]);
  J.out[idx] = f2bf(v);
}

// ---- legacy 128x128 MFMA GEMM (kept for phase-3 mixed-K job) ----
__device__ __forceinline__ void stage_bf16_async(const u16* __restrict__ G, size_t rbase,
                                                 int lda, int k0, u16* lds, int w, int lane) {
  #pragma unroll
  for (int t = 0; t < 2; ++t) {
    const int rr = (w << 5) + (t << 4) + (lane >> 2);
    const u16* gp = G + (rbase + rr) * (size_t)lda + k0 + ((lane & 3) << 3);
    __builtin_amdgcn_global_load_lds(
        (const __attribute__((address_space(1))) void*)gp,
        (__attribute__((address_space(3))) void*)(lds + (((w << 5) + (t << 4)) * 32)),
        16, 0, 0);
  }
}

__device__ __forceinline__ void stage_f32_manual(const float* __restrict__ G, int row0,
                                                 int lda, int k0, int Kreal,
                                                 u16* lds, int tid) {
  const int r = tid >> 1, half = tid & 1;
  const float* gp = G + (size_t)(row0 + r) * lda + k0 + (half << 4);
  #pragma unroll
  for (int qq = 0; qq < 4; ++qq) {
    const int kk = k0 + (half << 4) + (qq << 2);
    float4 v = make_float4(0.f, 0.f, 0.f, 0.f);
    if (kk < Kreal) v = *(const float4*)(gp + (qq << 2));
    ushort4 o;
    o.x = f2bf(v.x); o.y = f2bf(v.y); o.z = f2bf(v.z); o.w = f2bf(v.w);
    *(ushort4*)(lds + r * 32 + (half << 4) + (qq << 2)) = o;
  }
}

__device__ __forceinline__ void kloop(int am, const void* __restrict__ A, int lda,
                                      int Kreal, int Kpad, const u16* __restrict__ B,
                                      u16* As, u16* Bs, f32x4 (&acc)[4][4],
                                      int row0, int col0,
                                      int tid, int lane, int w, int wm, int wn, int ml, int q) {
  for (int k0 = 0; k0 < Kpad; k0 += 32) {
    if (am == 0) stage_bf16_async((const u16*)A, (size_t)row0, lda, k0, As, w, lane);
    else         stage_f32_manual((const float*)A, row0, lda, k0, Kreal, As, tid);
    stage_bf16_async(B, (size_t)col0, Kpad, k0, Bs, w, lane);
    __syncthreads();
    short8 af[4], bfr[4];
    #pragma unroll
    for (int i = 0; i < 4; ++i)
      af[i] = *(const short8*)(As + ((wm << 6) + (i << 4) + ml) * 32 + (q << 3));
    #pragma unroll
    for (int j = 0; j < 4; ++j)
      bfr[j] = *(const short8*)(Bs + ((wn << 6) + (j << 4) + ml) * 32 + (q << 3));
    #pragma unroll
    for (int i = 0; i < 4; ++i)
      #pragma unroll
      for (int j = 0; j < 4; ++j)
        acc[i][j] = __builtin_amdgcn_mfma_f32_16x16x32_bf16(af[i], bfr[j], acc[i][j], 0, 0, 0);
    __syncthreads();
  }
}

struct GJob {
  const void* A1; const u16* B1;
  const void* A2; const u16* B2;
  const void* bias; void* C;
  int lda1, K1real, K1pad, am1;
  int lda2, K2real, K2pad, am2;   // am2 = -1 -> no second pair
  int inBias, ldc, Nreal, Npad, relu, cf32;
  int gx, gy, blk0;               // tile grid; gy % 8 == 0
};
struct GPack { GJob j[2]; int nj; };

__global__ __launch_bounds__(256) void mfma_jobs(const int* __restrict__ flag, GPack P) {
  const int b = blockIdx.x;
  int ji = 0;
  if (P.nj > 1 && b >= P.j[1].blk0) ji = 1;
  const GJob J = P.j[ji];
  const int t = b - J.blk0;
  const int xcd = t & 7, s = t >> 3;
  const int row_t = xcd * (J.gy >> 3) + s / J.gx;
  const int col_t = s % J.gx;
  const int row0 = row_t << 7;
  const int col0 = col_t << 7;

  __shared__ __attribute__((aligned(16))) u16 As[128 * 32];
  __shared__ __attribute__((aligned(16))) u16 Bs[128 * 32];
  const int tid = threadIdx.x;
  const int lane = tid & 63;
  const int w = tid >> 6;
  const int wm = w >> 1, wn = w & 1;
  const int ml = lane & 15, q = lane >> 4;

  f32x4 acc[4][4];
  #pragma unroll
  for (int i = 0; i < 4; ++i)
    #pragma unroll
    for (int j = 0; j < 4; ++j) {
      f32x4 z = {0.f, 0.f, 0.f, 0.f};
      acc[i][j] = z;
    }

  kloop(J.am1, J.A1, J.lda1, J.K1real, J.K1pad, J.B1, As, Bs, acc,
        row0, col0, tid, lane, w, wm, wn, ml, q);
  if (J.am2 >= 0)
    kloop(J.am2, J.A2, J.lda2, J.K2real, J.K2pad, J.B2, As, Bs, acc,
          row0, col0, tid, lane, w, wm, wn, ml, q);

  const int fin = flag[0];
  // C/D layout (m89-verified): col = lane&15, row = (lane>>4)*4 + reg
  #pragma unroll
  for (int j = 0; j < 4; ++j) {
    const int col = col0 + (wn << 6) + (j << 4) + ml;
    if (col >= J.Npad) continue;
    float bv = 0.f;
    if (J.bias && col < J.Nreal) bv = ld1(J.bias, col, J.inBias ? fin : 0);
    #pragma unroll
    for (int i = 0; i < 4; ++i) {
      #pragma unroll
      for (int r = 0; r < 4; ++r) {
        const int row = row0 + (wm << 6) + (i << 4) + (q << 2) + r;
        float v = 0.f;
        if (col < J.Nreal) {
          v = acc[i][j][r] + bv;
          if (J.relu) v = fmaxf(v, 0.f);
        }
        if (J.cf32) ((float*)J.C)[(size_t)row * J.ldc + col] = v;
        else        ((u16*)J.C)[(size_t)row * J.ldc + col] = f2bf(v);
      }
    }
  }
}

// ======================================================================
// 256x256 8-phase GEMM (T1+T2+T3+T4+T5), bf16 A/B.  (R4-proven)
// Multi-job: per-job grid segment with bijective XCD swizzle (nwg%8==0).
// 8 waves (2M x 4N), BK=64 split in two 32-k halves; LDS 128 KiB 2-dbuf.
// Counted vmcnt(4) at end-P1 / end-P3. Epilogue via per-wave LDS
// transpose -> coalesced ushort8 stores (killed 2.4x write amplification).
// ======================================================================

struct G2Job {
  const u16* A1; const u16* B1;
  const u16* A2; const u16* B2;   // second K-segment (dual-A fused GEMM)
  const void* bias; u16* C;
  int ldk;        // K stride in elements, same for A and B^T
  int nt1, nt2;   // 64-wide K tiles per segment (nt2=0 -> single segment)
  int gx;         // column tiles (N/256)
  int ldc, Nreal, relu, inBias;
  int nwg, blk0;  // grid segment
};
struct G2Pack { G2Job j[2]; int nj; };

#define L2_HALF 16384
#define L2_BUF  65536

__device__ __forceinline__ void barrier_f() {
  asm volatile("" ::: "memory");
  __builtin_amdgcn_s_barrier();
  asm volatile("" ::: "memory");
}

__device__ __forceinline__ void read4f(const char* base, short8 (&dst)[4]) {
  #pragma unroll
  for (int i = 0; i < 4; ++i) dst[i] = *(const short8*)(base + i * 1024);
}

__device__ __forceinline__ void mfma16(f32x4 (&acc)[8][4], const short8 (&af)[4],
                                       const short8 (&bfr)[4], int mg) {
  __builtin_amdgcn_s_setprio(1);
  #pragma unroll
  for (int i = 0; i < 4; ++i)
    #pragma unroll
    for (int n = 0; n < 4; ++n)
      acc[mg * 4 + i][n] =
          __builtin_amdgcn_mfma_f32_16x16x32_bf16(af[i], bfr[n], acc[mg * 4 + i][n], 0, 0, 0);
  __builtin_amdgcn_s_setprio(0);
}

__global__ __launch_bounds__(512, 2) void mfma256(const int* __restrict__ flag, G2Pack P) {
  __shared__ __attribute__((aligned(16))) u16 LDS[65536];  // 128 KiB
  char* ldsc = (char*)LDS;

  const int bid = blockIdx.x;
  const int ji = (P.nj > 1 && bid >= P.j[1].blk0) ? 1 : 0;
  const G2Job J = P.j[ji];
  const int b = bid - J.blk0;
  // T1: bijective XCD swizzle within the job's grid segment (nwg % 8 == 0)
  const int wg = (b & 7) * (J.nwg >> 3) + (b >> 3);
  const int rt = wg / J.gx, ct = wg % J.gx;
  const int row0 = rt << 8, col0 = ct << 8;

  const int tid = threadIdx.x;
  const int lane = tid & 63, w = tid >> 6;
  const int wm = w >> 2, wn = w & 3;
  const int q = lane >> 4, ml = lane & 15;
  const int ldk = J.ldk;
  const int nt = J.nt1 + J.nt2;

  // read-side swizzled in-subtile byte offset (lane-constant)
  const int swzr = (ml * 64 + q * 16) ^ (((ml >> 1) & 3) << 4);
  // stage-side: which (row, col) of the subtile this lane must fetch so
  // that the LINEAR DMA write lands it at its swizzled LDS position
  const int ub = (lane * 16) ^ (((lane >> 3) & 3) << 4);
  const int r_in = ub >> 6, c_in = (ub & 63) >> 1;

  f32x4 acc[8][4];
  #pragma unroll
  for (int m = 0; m < 8; ++m)
    #pragma unroll
    for (int n = 0; n < 4; ++n) { f32x4 z = {0.f, 0.f, 0.f, 0.f}; acc[m][n] = z; }

  // stage one half-tile slice: this wave covers subtiles w*2 and w*2+1
  auto stage = [&](int cb2, const u16* __restrict__ G, int rb, int kc, int boff, int kh) {
    char* lb = ldsc + cb2 * L2_BUF + boff + kh * L2_HALF + w * 2048;
    const u16* g0 = G + (size_t)(rb + w * 32 + r_in) * (size_t)ldk + kc;
    __builtin_amdgcn_global_load_lds((const __attribute__((address_space(1))) void*)g0,
        (__attribute__((address_space(3))) void*)lb, 16, 0, 0);
    const u16* g1 = g0 + (size_t)16 * ldk;
    __builtin_amdgcn_global_load_lds((const __attribute__((address_space(1))) void*)g1,
        (__attribute__((address_space(3))) void*)(lb + 1024), 16, 0, 0);
  };

  // prologue: stage tile 0 (4 half-tiles, 8 loads/thread); release kh0
  stage(0, J.A1, row0, 0 + c_in, 0, 0);
  stage(0, J.B1, col0, 0 + c_in, 32768, 0);
  stage(0, J.A1, row0, 32 + c_in, 0, 1);
  stage(0, J.B1, col0, 32 + c_in, 32768, 1);
  asm volatile("s_waitcnt vmcnt(4)" ::: "memory");
  barrier_f();

  int cb = 0;
  #pragma unroll 1
  for (int kt = 0; kt < nt; ++kt) {
    const int nk = (kt + 1 < nt) ? kt + 1 : kt;  // last tile re-stages itself (dead data)
    const u16* An = (nk < J.nt1) ? J.A1 : J.A2;
    const u16* Bn = (nk < J.nt1) ? J.B1 : J.B2;
    const int kb = ((nk < J.nt1) ? nk : nk - J.nt1) << 6;
    const char* abase = ldsc + cb * L2_BUF + wm * 8192 + swzr;
    const char* bbase = ldsc + cb * L2_BUF + 32768 + wn * 4096 + swzr;
    short8 a0[4], a1[4], bfr[4];

    // ---- P0: kstep 0, m-frags 0-3 ----
    read4f(abase, a0);
    read4f(bbase, bfr);
    stage(cb ^ 1, An, row0, kb + c_in, 0, 0);
    barrier_f();
    mfma16(acc, a0, bfr, 0);
    barrier_f();
    // ---- P1: kstep 0, m-frags 4-7 ----
    read4f(abase + 4096, a1);
    stage(cb ^ 1, Bn, col0, kb + c_in, 32768, 0);
    barrier_f();
    mfma16(acc, a1, bfr, 1);
    asm volatile("s_waitcnt vmcnt(4)" ::: "memory");  // prev-tile kh1 stages landed
    barrier_f();
    // ---- P2: kstep 1, m-frags 0-3 ----
    read4f(abase + L2_HALF, a0);
    read4f(bbase + L2_HALF, bfr);
    stage(cb ^ 1, An, row0, kb + 32 + c_in, 0, 1);
    barrier_f();
    mfma16(acc, a0, bfr, 0);
    barrier_f();
    // ---- P3: kstep 1, m-frags 4-7 ----
    read4f(abase + L2_HALF + 4096, a1);
    stage(cb ^ 1, Bn, col0, kb + 32 + c_in, 32768, 1);
    barrier_f();
    mfma16(acc, a1, bfr, 1);
    asm volatile("s_waitcnt vmcnt(4)" ::: "memory");  // this-tile kh0 stages landed
    barrier_f();
    cb ^= 1;
  }
  // drain outstanding LDS-DMA, then barrier: LDS is dead, reuse for epilogue
  asm volatile("s_waitcnt vmcnt(0)" ::: "memory");
  barrier_f();

  // ---- epilogue: per-wave LDS transpose -> coalesced ushort8 stores ----
  {
    u16* myL = LDS + w * 8192;
    const int fin = flag[0];
    #pragma unroll
    for (int n = 0; n < 4; ++n) {
      const int col_l = n * 16 + ml;
      const int gcol = col0 + wn * 64 + col_l;
      const bool valid = (gcol < J.Nreal);
      float bv = 0.f;
      if (J.bias && valid) bv = ld1(J.bias, gcol, J.inBias ? fin : 0);
      #pragma unroll
      for (int m = 0; m < 8; ++m) {
        #pragma unroll
        for (int r = 0; r < 4; ++r) {
          const int row_l = m * 16 + q * 4 + r;
          float v = 0.f;
          if (valid) {
            v = acc[m][n][r] + bv;
            if (J.relu) v = fmaxf(v, 0.f);
          }
          myL[row_l * 64 + (col_l ^ ((row_l & 7) << 3))] = f2bf(v);
        }
      }
    }
    // read back row-contiguous (wave-private slice; lgkmcnt orders ds ops)
    const int rl0 = lane >> 3, cc = lane & 7;
    #pragma unroll
    for (int t = 0; t < 16; ++t) {
      const int row_l = t * 8 + rl0;
      const short8 vv = *(const short8*)(myL + row_l * 64 + ((cc * 8) ^ ((row_l & 7) << 3)));
      const int grow = row0 + wm * 128 + row_l;
      const int gcol = col0 + wn * 64 + cc * 8;
      if (gcol < J.ldc)
        *(short8*)(&J.C[(size_t)grow * J.ldc + gcol]) = vv;
    }
  }
}

// --- CSR build ---
__global__ void cnt_kernel(const int* __restrict__ edst, int* __restrict__ cnt) {
  const int i = blockIdx.x * 256 + threadIdx.x;
  if (i < EE) atomicAdd(&cnt[edst[i]], 1);
}

__global__ __launch_bounds__(1024) void scan_kernel(const int* __restrict__ cnt,
                                                    int* __restrict__ offs,
                                                    int* __restrict__ woffs) {
  __shared__ int part[1024];
  const int t = threadIdx.x;
  const int base = t * 16;
  int loc[16];
  int s = 0;
  #pragma unroll
  for (int i = 0; i < 16; ++i) { loc[i] = s; s += cnt[base + i]; }
  part[t] = s;
  __syncthreads();
  for (int off = 1; off < 1024; off <<= 1) {
    int v = (t >= off) ? part[t - off] : 0;
    __syncthreads();
    part[t] += v;
    __syncthreads();
  }
  const int chunk_excl = (t == 0) ? 0 : part[t - 1];
  #pragma unroll
  for (int i = 0; i < 16; ++i) {
    int o = chunk_excl + loc[i];
    offs[base + i] = o;
    woffs[base + i] = o;
  }
  if (t == 1023) offs[NN] = part[1023];
}

__global__ void scatter_kernel(const int* __restrict__ esrc, const int* __restrict__ edst,
                               int* __restrict__ woffs,
                               int* __restrict__ order, int* __restrict__ srcs) {
  const int e = blockIdx.x * 256 + threadIdx.x;
  if (e < EE) {
    const int d = edst[e];
    const int pos = atomicAdd(&woffs[d], 1);
    order[pos] = e;
    srcs[pos] = esrc[e];
  }
}

// ======================================================================
// appearance aggregation, f32 fast path.  2 NODES PER BLOCK, interleaved
// 4-edge groups: 8 independent P12 gathers in flight per iteration (2x MLP
// vs R5; R5 showed VALUBusy 57% / dur -6% after halving issue -> latency-
// bound on gathers). Weights shared by both nodes. Loop bounds are block-
// uniform (both CSR ranges depend only on blockIdx) -> no divergence.
// ======================================================================
__device__ __forceinline__ void edge4_core(
    const int* __restrict__ ee, const ushort4* __restrict__ pm,
    const float* __restrict__ base, float* __restrict__ a,
    const f32x2 (&w2)[8][4], const float* __restrict__ s_f)
{
  f32x2 u2[4][4];
  #pragma unroll
  for (int m = 0; m < 4; ++m)
    #pragma unroll
    for (int c = 0; c < 4; ++c) u2[m][c] = f32x2{0.f, 0.f};

  f32x2 sA[4][4];
  // k-chunk A: k 0..7
  #pragma unroll
  for (int m = 0; m < 4; ++m) {
    const float4 q0 = *(const float4*)(s_f + (size_t)ee[m] * DS);
    const float4 q1 = *(const float4*)(s_f + (size_t)ee[m] * DS + 4);
    sA[m][0] = f32x2{q0.x, q0.y}; sA[m][1] = f32x2{q0.z, q0.w};
    sA[m][2] = f32x2{q1.x, q1.y}; sA[m][3] = f32x2{q1.z, q1.w};
  }
  #pragma unroll
  for (int h = 0; h < 4; ++h)
    #pragma unroll
    for (int m = 0; m < 4; ++m)
      #pragma unroll
      for (int c = 0; c < 4; ++c)
        u2[m][c] = __builtin_elementwise_fma(sA[m][h], w2[h][c], u2[m][c]);
  // k-chunk B: k 8..15
  #pragma unroll
  for (int m = 0; m < 4; ++m) {
    const float4 q2 = *(const float4*)(s_f + (size_t)ee[m] * DS + 8);
    const float4 q3 = *(const float4*)(s_f + (size_t)ee[m] * DS + 12);
    sA[m][0] = f32x2{q2.x, q2.y}; sA[m][1] = f32x2{q2.z, q2.w};
    sA[m][2] = f32x2{q3.x, q3.y}; sA[m][3] = f32x2{q3.z, q3.w};
  }
  #pragma unroll
  for (int h = 0; h < 4; ++h)
    #pragma unroll
    for (int m = 0; m < 4; ++m)
      #pragma unroll
      for (int c = 0; c < 4; ++c)
        u2[m][c] = __builtin_elementwise_fma(sA[m][h], w2[h + 4][c], u2[m][c]);

  #pragma unroll
  for (int m = 0; m < 4; ++m) {
    a[0] += fmaxf(u2[m][0].x + u2[m][0].y + bf2f(pm[m].x) + base[0], 0.f);
    a[1] += fmaxf(u2[m][1].x + u2[m][1].y + bf2f(pm[m].y) + base[1], 0.f);
    a[2] += fmaxf(u2[m][2].x + u2[m][2].y + bf2f(pm[m].z) + base[2], 0.f);
    a[3] += fmaxf(u2[m][3].x + u2[m][3].y + bf2f(pm[m].w) + base[3], 0.f);
  }
}

__device__ __forceinline__ void edge1_core(
    int e, const ushort4 p1, const float* __restrict__ base, float* __restrict__ a,
    const f32x2 (&w2)[8][4], const float* __restrict__ s_f)
{
  f32x2 u2[4] = {f32x2{0.f, 0.f}, f32x2{0.f, 0.f}, f32x2{0.f, 0.f}, f32x2{0.f, 0.f}};
  #pragma unroll
  for (int h4 = 0; h4 < 4; ++h4) {
    const float4 qq = *(const float4*)(s_f + (size_t)e * DS + h4 * 4);
    const f32x2 s0 = f32x2{qq.x, qq.y}, s1 = f32x2{qq.z, qq.w};
    #pragma unroll
    for (int c = 0; c < 4; ++c) {
      u2[c] = __builtin_elementwise_fma(s0, w2[h4 * 2][c], u2[c]);
      u2[c] = __builtin_elementwise_fma(s1, w2[h4 * 2 + 1][c], u2[c]);
    }
  }
  a[0] += fmaxf(u2[0].x + u2[0].y + bf2f(p1.x) + base[0], 0.f);
  a[1] += fmaxf(u2[1].x + u2[1].y + bf2f(p1.y) + base[1], 0.f);
  a[2] += fmaxf(u2[2].x + u2[2].y + bf2f(p1.z) + base[2], 0.f);
  a[3] += fmaxf(u2[3].x + u2[3].y + bf2f(p1.w) + base[3], 0.f);
}

__device__ __forceinline__ void app_agg_f32(
    const u16* __restrict__ P12, const float* __restrict__ s_f,
    const float* __restrict__ W_es, const float* __restrict__ b_e,
    const int* __restrict__ offs, const int* __restrict__ order,
    const int* __restrict__ srcs, u16* __restrict__ aggn)
{
  const int nA = blockIdx.x * 2, nB = nA + 1;
  const int tid = threadIdx.x;
  const int c4 = tid << 2;

  // weight pairs across k: w2[h][c] = {W[2h][c4+c], W[2h+1][c4+c]}
  f32x2 w2[8][4];
  #pragma unroll
  for (int h = 0; h < 8; ++h) {
    const float4 r0 = *(const float4*)(W_es + (size_t)(2 * h) * DF + c4);
    const float4 r1 = *(const float4*)(W_es + (size_t)(2 * h + 1) * DF + c4);
    w2[h][0] = f32x2{r0.x, r1.x}; w2[h][1] = f32x2{r0.y, r1.y};
    w2[h][2] = f32x2{r0.z, r1.z}; w2[h][3] = f32x2{r0.w, r1.w};
  }
  const float4 be = *(const float4*)(b_e + c4);
  const ushort4 p2A = *(const ushort4*)(P12 + ((size_t)(unsigned)(nA << 11)) + 1024 + c4);
  const ushort4 p2B = *(const ushort4*)(P12 + ((size_t)(unsigned)(nB << 11)) + 1024 + c4);
  float baseA[4], baseB[4];
  baseA[0] = bf2f(p2A.x) + be.x; baseA[1] = bf2f(p2A.y) + be.y;
  baseA[2] = bf2f(p2A.z) + be.z; baseA[3] = bf2f(p2A.w) + be.w;
  baseB[0] = bf2f(p2B.x) + be.x; baseB[1] = bf2f(p2B.y) + be.y;
  baseB[2] = bf2f(p2B.z) + be.z; baseB[3] = bf2f(p2B.w) + be.w;

  int jA = offs[nA];
  const int eA = offs[nA + 1];
  int jB = offs[nB];
  const int eB = offs[nB + 1];
  float aA[4] = {0.f, 0.f, 0.f, 0.f}, aB[4] = {0.f, 0.f, 0.f, 0.f};

  // interleaved main loop: 4 gathers from each node's edge list in flight
  while (jA + 4 <= eA && jB + 4 <= eB) {
    int eeA[4], eeB[4];
    ushort4 pmA[4], pmB[4];
    #pragma unroll
    for (int m = 0; m < 4; ++m) {
      eeA[m] = order[jA + m];
      pmA[m] = *(const ushort4*)(P12 + ((size_t)(unsigned)(srcs[jA + m] << 11)) + c4);
    }
    #pragma unroll
    for (int m = 0; m < 4; ++m) {
      eeB[m] = order[jB + m];
      pmB[m] = *(const ushort4*)(P12 + ((size_t)(unsigned)(srcs[jB + m] << 11)) + c4);
    }
    edge4_core(eeA, pmA, baseA, aA, w2, s_f);   // B's gathers drain under A's FMAs
    edge4_core(eeB, pmB, baseB, aB, w2, s_f);
    jA += 4; jB += 4;
  }
  // drain A in 4-groups
  for (; jA + 4 <= eA; jA += 4) {
    int ee[4]; ushort4 pm[4];
    #pragma unroll
    for (int m = 0; m < 4; ++m) {
      ee[m] = order[jA + m];
      pm[m] = *(const ushort4*)(P12 + ((size_t)(unsigned)(srcs[jA + m] << 11)) + c4);
    }
    edge4_core(ee, pm, baseA, aA, w2, s_f);
  }
  // drain B in 4-groups
  for (; jB + 4 <= eB; jB += 4) {
    int ee[4]; ushort4 pm[4];
    #pragma unroll
    for (int m = 0; m < 4; ++m) {
      ee[m] = order[jB + m];
      pm[m] = *(const ushort4*)(P12 + ((size_t)(unsigned)(srcs[jB + m] << 11)) + c4);
    }
    edge4_core(ee, pm, baseB, aB, w2, s_f);
  }
  // scalar tails
  for (; jA < eA; ++jA) {
    const ushort4 p1 = *(const ushort4*)(P12 + ((size_t)(unsigned)(srcs[jA] << 11)) + c4);
    edge1_core(order[jA], p1, baseA, aA, w2, s_f);
  }
  for (; jB < eB; ++jB) {
    const ushort4 p1 = *(const ushort4*)(P12 + ((size_t)(unsigned)(srcs[jB] << 11)) + c4);
    edge1_core(order[jB], p1, baseB, aB, w2, s_f);
  }

  const float invA = 1.f / fmaxf((float)(eA - offs[nA]), 1.f);
  const float invB = 1.f / fmaxf((float)(eB - offs[nB]), 1.f);
  ushort4 oA, oB;
  oA.x = f2bf(aA[0] * invA); oA.y = f2bf(aA[1] * invA);
  oA.z = f2bf(aA[2] * invA); oA.w = f2bf(aA[3] * invA);
  oB.x = f2bf(aB[0] * invB); oB.y = f2bf(aB[1] * invB);
  oB.z = f2bf(aB[2] * invB); oB.w = f2bf(aB[3] * invB);
  *(ushort4*)(aggn + (size_t)nA * DF + c4) = oA;
  *(ushort4*)(aggn + (size_t)nB * DF + c4) = oB;
}

// bf16-input fallback (generic scalar path, correctness-only), 2 nodes/block
__device__ __forceinline__ void app_agg_bf16(
    const u16* __restrict__ P12, const void* __restrict__ s_f,
    const void* __restrict__ W_eb, const void* __restrict__ b_e,
    const int* __restrict__ offs, const int* __restrict__ order,
    const int* __restrict__ srcs, u16* __restrict__ aggn)
{
  const int tid = threadIdx.x;
  const int c4 = tid << 2;
  const void* W_es = eoff(W_eb, (size_t)2 * DF * DF, 0);

  float wx[16], wy[16], wz[16], ww[16];
  #pragma unroll
  for (int k = 0; k < 16; ++k)
    ld4(W_es, (size_t)k * DF + c4, 0, wx[k], wy[k], wz[k], ww[k]);

  float be0, be1, be2, be3;
  ld4(b_e, c4, 0, be0, be1, be2, be3);

  for (int half = 0; half < 2; ++half) {
    const int n = blockIdx.x * 2 + half;
    const ushort4 p2 = *(const ushort4*)(P12 + ((size_t)(unsigned)(n << 11)) + 1024 + c4);
    const float base0 = bf2f(p2.x) + be0;
    const float base1 = bf2f(p2.y) + be1;
    const float base2 = bf2f(p2.z) + be2;
    const float base3 = bf2f(p2.w) + be3;

    const int beg = offs[n], end = offs[n + 1];
    float a0 = 0.f, a1 = 0.f, a2 = 0.f, a3 = 0.f;
    for (int j = beg; j < end; ++j) {
      const int e = order[j], s = srcs[j];
      float sf[16];
      #pragma unroll
      for (int k = 0; k < 16; k += 4)
        ld4(s_f, (size_t)e * DS + k, 0, sf[k], sf[k + 1], sf[k + 2], sf[k + 3]);
      const ushort4 p1 = *(const ushort4*)(P12 + ((size_t)(unsigned)(s << 11)) + c4);
      float v0 = bf2f(p1.x) + base0;
      float v1 = bf2f(p1.y) + base1;
      float v2 = bf2f(p1.z) + base2;
      float v3 = bf2f(p1.w) + base3;
      #pragma unroll
      for (int k = 0; k < 16; ++k) {
        v0 = fmaf(sf[k], wx[k], v0);
        v1 = fmaf(sf[k], wy[k], v1);
        v2 = fmaf(sf[k], wz[k], v2);
        v3 = fmaf(sf[k], ww[k], v3);
      }
      a0 += fmaxf(v0, 0.f); a1 += fmaxf(v1, 0.f);
      a2 += fmaxf(v2, 0.f); a3 += fmaxf(v3, 0.f);
    }
    const float inv = 1.f / fmaxf((float)(end - beg), 1.f);
    ushort4 o;
    o.x = f2bf(a0 * inv); o.y = f2bf(a1 * inv);
    o.z = f2bf(a2 * inv); o.w = f2bf(a3 * inv);
    *(ushort4*)(aggn + (size_t)n * DF + c4) = o;
  }
}

__global__ __launch_bounds__(256) void app_agg(
    const int* __restrict__ flag,
    const u16* __restrict__ P12, const void* __restrict__ s_f,
    const void* __restrict__ W_eb, const void* __restrict__ b_e,
    const int* __restrict__ offs, const int* __restrict__ order,
    const int* __restrict__ srcs, u16* __restrict__ aggn)
{
  if (flag[0])
    app_agg_f32(P12, (const float*)s_f, (const float*)W_eb + (size_t)2 * DF * DF,
                (const float*)b_e, offs, order, srcs, aggn);
  else
    app_agg_bf16(P12, s_f, W_eb, b_e, offs, order, srcs, aggn);
}

// language aggregation, vectorized: 8 nodes/block x 40 threads x ushort8.
// Q12 interleaved [n][768] (Q1 @0 | Q2 @384); out [NN][DLP] zero-pad.
__global__ __launch_bounds__(320) void lang_agg(
    const int* __restrict__ flag,
    const u16* __restrict__ Q12, const void* __restrict__ b_el,
    const int* __restrict__ offs, const int* __restrict__ srcs,
    u16* __restrict__ aggln)
{
  const int fin = flag[0];
  const int tid = threadIdx.x;
  const int g = tid / 40;            // local node 0..7
  const int c8 = (tid - g * 40) * 8; // 0..312
  const int n = blockIdx.x * 8 + g;

  // base[i] = Q2[n][c8+i] + b_el[c8+i]; pad cols (>=300) have Q2=0, b_el=0
  const short8 q2 = *(const short8*)(Q12 + (size_t)n * 768 + 384 + c8);
  float base[8];
  #pragma unroll
  for (int i = 0; i < 8; ++i)
    base[i] = bf2f((u16)q2[i]) + ((c8 + i < DL) ? ld1(b_el, c8 + i, fin) : 0.f);

  const int beg = offs[n], end = offs[n + 1];
  float s0[8] = {0, 0, 0, 0, 0, 0, 0, 0}, s1[8] = {0, 0, 0, 0, 0, 0, 0, 0};
  int j = beg;
  for (; j + 2 <= end; j += 2) {
    const int sa = srcs[j], sb = srcs[j + 1];
    const short8 va = *(const short8*)(Q12 + (size_t)sa * 768 + c8);
    const short8 vb = *(const short8*)(Q12 + (size_t)sb * 768 + c8);
    #pragma unroll
    for (int i = 0; i < 8; ++i) {
      s0[i] += fmaxf(bf2f((u16)va[i]) + base[i], 0.f);
      s1[i] += fmaxf(bf2f((u16)vb[i]) + base[i], 0.f);
    }
  }
  if (j < end) {
    const int sa = srcs[j];
    const short8 va = *(const short8*)(Q12 + (size_t)sa * 768 + c8);
    #pragma unroll
    for (int i = 0; i < 8; ++i) s0[i] += fmaxf(bf2f((u16)va[i]) + base[i], 0.f);
  }
  const float inv = 1.f / fmaxf((float)(end - beg), 1.f);
  short8 o;
  #pragma unroll
  for (int i = 0; i < 8; ++i) o[i] = (short)f2bf((s0[i] + s1[i]) * inv);
  *(short8*)(aggln + (size_t)n * DLP + c8) = o;
}

// pred[e] = RdRs[dst,0:117] + RdRs[src,128:245] + s_f_ro[e]@Wp_s + b_p
__global__ __launch_bounds__(256) void readout_kernel(
    const int* __restrict__ flag,
    const float* __restrict__ RdRs,
    const void* __restrict__ s_f_ro,
    const void* __restrict__ W_pb, size_t offWps,
    const void* __restrict__ b_p,
    const int* __restrict__ rsrc, const int* __restrict__ rdst, void* __restrict__ out)
{
  const int fin = flag[0];
  __shared__ float wps[16 * NC];
  const void* Wp_s = eoff(W_pb, offWps, fin);
  const int tid = threadIdx.x;
  for (int i = tid; i < 16 * NC; i += 256) wps[i] = ld1(Wp_s, i, fin);
  __syncthreads();
  const int slot = tid >> 7;        // 0 or 1
  const int c = tid & 127;
  const float bp = (c < NC) ? ld1(b_p, c, fin) : 0.f;

  const int e0 = (blockIdx.x << 3) + slot;
  #pragma unroll
  for (int ee = 0; ee < 8; ee += 2) {
    const int e = e0 + ee;
    const int s = rsrc[e];
    const int d = rdst[e];
    if (c < NC) {
      float acc = RdRs[(size_t)d * 256 + c] + RdRs[(size_t)s * 256 + 128 + c] + bp;
      #pragma unroll
      for (int k = 0; k < 16; ++k)
        acc = fmaf(ld1(s_f_ro, (size_t)e * DS + k, fin), wps[k * NC + c], acc);
      if (fin) ((float*)out)[(size_t)e * NC + c] = acc;
      else     ((u16*)out)[(size_t)e * NC + c] = f2bf(acc);
    }
  }
}

extern "C" void kernel_launch(void* const* d_in, const int* in_sizes, int n_in,
                              void* d_out, int out_size, void* d_ws, size_t ws_size,
                              hipStream_t stream)
{
  const void* feat  = d_in[0];
  const void* w2v   = d_in[1];
  const void* s_f   = d_in[2];
  const void* s_fro = d_in[3];
  const void* W_e   = d_in[4];
  const void* b_e   = d_in[5];
  const void* W_el  = d_in[6];
  const void* b_el  = d_in[7];
  const void* W_nu  = d_in[8];
  const void* b_nu  = d_in[9];
  const void* W_nul = d_in[10];
  const void* b_nul = d_in[11];
  const void* W_p   = d_in[12];
  const void* b_p   = d_in[13];
  const int* esrc  = (const int*)d_in[14];
  const int* edst  = (const int*)d_in[15];
  const int* rsrc  = (const int*)d_in[16];
  const int* rdst  = (const int*)d_in[17];

  // ---- workspace layout: ~183 MB ----
  char* p = (char*)d_ws;
  int* flag  = (int*)p; p += 256;
  int* cnt   = (int*)p; p += (size_t)NN * 4;
  int* offs  = (int*)p; p += (size_t)(NN + 64) * 4;
  int* woffs = (int*)p; p += (size_t)NN * 4;
  int* order = (int*)p; p += (size_t)EE * 4;
  int* srcs  = (int*)p; p += (size_t)EE * 4;
  u16* featB  = (u16*)p; p += (size_t)NN * DF * 2;        // 32 MB bf16 feat
  u16* We12T  = (u16*)p; p += (size_t)2 * DF * DF * 2;    // [2048][1024]
  u16* Wnu1T  = (u16*)p; p += (size_t)DF * DF * 2;
  u16* Wnu2T  = (u16*)p; p += (size_t)DF * DF * 2;
  u16* Wel12T = (u16*)p; p += (size_t)2 * DLN * DLP * 2;  // [768][320]
  u16* Wnul1T = (u16*)p; p += (size_t)DLN * DLP * 2;
  u16* Wnul2T = (u16*)p; p += (size_t)DLN * DLP * 2;
  u16* WpFT2  = (u16*)p; p += (size_t)2 * NCP * DF * 2;   // [256][1024] (Rd-F | Rs-F)
  u16* WpLT2  = (u16*)p; p += (size_t)2 * NCP * DLP * 2;  // [256][320]  (Rd-L | Rs-L)
  u16* P12   = (u16*)p; p += (size_t)NN * 2048 * 2;       // 64 MB; later newf+newl
  u16* Q12   = (u16*)p; p += (size_t)NN * 768 * 2;        // 24 MB; later RdRs (16 MB f32)
  u16* aggln = (u16*)p; p += (size_t)NN * DLP * 2;        // 10 MB
  u16* aggn  = (u16*)p; p += (size_t)NN * DF * 2;         // 32 MB
  u16* w2vB  = (u16*)p; p += (size_t)NN * DLP * 2;        // 10.5 MB bf16 K-padded w2v
  // aliases (stream-ordered: P12 dead after app_agg; Q12 dead after lang_agg)
  u16* newf = P12;
  u16* newl = P12 + (size_t)NN * DF;
  float* RdRs = (float*)Q12;

  detect_kernel<<<1, 64, 0, stream>>>((const unsigned int*)feat, flag);
  hipMemsetAsync(cnt, 0, (size_t)NN * 4, stream);
  cast_bf16<<<(NN * DF / 8 + 255) / 256, 256, 0, stream>>>(flag, feat, featB, NN * DF / 8);
  cast_w2v<<<(NN * 80 + 255) / 256, 256, 0, stream>>>(flag, w2v, w2vB);

  // ---- fused weight prep (12 transposes, one launch) ----
  TPack2 tp{};
  int tb = 0, tn = 0;
  auto T = [&](const void* W, long off, int Kr, int Nr, int Nstr, u16* out, int Kp, int Np) {
    tp.j[tn] = TJob2{W, off, out, Kr, Nr, Nstr, Kp, Np, tb};
    tb += (Np * Kp + 255) / 256;
    ++tn;
  };
  T(W_e,   0,                   DF, DF, DF, We12T,                     DF, DF);
  T(W_e,   (long)DF * DF,       DF, DF, DF, We12T + (size_t)DF * DF,   DF, DF);
  T(W_nu,  0,                   DF, DF, DF, Wnu1T, DF, DF);
  T(W_nu,  (long)DF * DF,       DF, DF, DF, Wnu2T, DF, DF);
  T(W_el,  0,                   DL, DL, DL, Wel12T,                     DLP, DLN);
  T(W_el,  (long)DL * DL,       DL, DL, DL, Wel12T + (size_t)DLN * DLP, DLP, DLN);
  T(W_nul, 0,                   DL, DL, DL, Wnul1T, DLP, DLN);
  T(W_nul, (long)DL * DL,       DL, DL, DL, Wnul2T, DLP, DLN);
  T(W_p,   0,                                DF, NC, NC, WpFT2,                     DF,  NCP);
  T(W_p,   (long)(DF + DL + DS + DL) * NC,   DF, NC, NC, WpFT2 + (size_t)NCP * DF,  DF,  NCP);
  T(W_p,   (long)DF * NC,                    DL, NC, NC, WpLT2,                     DLP, NCP);
  T(W_p,   (long)(DF + DL + DS) * NC,        DL, NC, NC, WpLT2 + (size_t)NCP * DLP, DLP, NCP);
  tp.nj = tn;
  prep_weights2<<<tb, 256, 0, stream>>>(flag, tp);

  // ---- CSR build ----
  cnt_kernel<<<EE / 256, 256, 0, stream>>>(edst, cnt);
  scan_kernel<<<1, 1024, 0, stream>>>(cnt, offs, woffs);
  scatter_kernel<<<EE / 256, 256, 0, stream>>>(esrc, edst, woffs, order, srcs);

  // ---- GEMM phase 1 (one launch, 2 jobs): P12 = featB @ We12T^T  |  Q12 = w2vB @ Wel12T^T
  {
    G2Pack g{};
    g.j[0] = G2Job{featB, We12T, nullptr, nullptr, nullptr, P12,
                   DF, 16, 0, 8, 2048, 2048, 0, 0, 512, 0};
    g.j[1] = G2Job{w2vB, Wel12T, nullptr, nullptr, nullptr, Q12,
                   DLP, 5, 0, 3, 768, 768, 0, 0, 192, 512};
    g.nj = 2;
    mfma256<<<704, 512, 0, stream>>>(flag, g);
  }

  // ---- aggregations (CSR, no atomics) ----
  lang_agg<<<NN / 8, 320, 0, stream>>>(flag, Q12, b_el, offs, srcs, aggln);
  app_agg<<<NN / 2, 256, 0, stream>>>(flag, P12, s_f, W_e, b_e, offs, order, srcs, aggn);

  // ---- GEMM phase 2 (one launch, 2 jobs): node updates (newf/newl alias P12) ----
  {
    G2Pack g{};
    g.j[0] = G2Job{featB, Wnu1T, aggn, Wnu2T, b_nu, newf,
                   DF, 16, 16, 4, DF, DF, 1, 1, 256, 0};
    g.j[1] = G2Job{w2vB, Wnul1T, aggln, Wnul2T, b_nul, newl,
                   DLP, 5, 5, 2, DLP, DL, 1, 1, 128, 256};
    g.nj = 2;
    mfma256<<<384, 512, 0, stream>>>(flag, g);
  }

  // ---- GEMM phase 3: fused readout projections (f32, [NN][256]: Rd | Rs) ----
  {
    GPack g{};
    g.j[0] = GJob{newf, WpFT2, newl, WpLT2, nullptr, RdRs,
                  DF, DF, DF, 0,    DLP, DLP, DLP, 0,
                  0, 256, 256, 256, 0, 1,    2, 128, 0};
    g.nj = 1;
    mfma_jobs<<<256, 256, 0, stream>>>(flag, g);
  }

  readout_kernel<<<ERO / 8, 256, 0, stream>>>(flag, RdRs, s_fro,
                                              W_p, (size_t)(DF + DL) * NC, b_p,
                                              rsrc, rdst, d_out);
}

// Round 8
// 570.982 us; speedup vs baseline: 1.0655x; 1.0655x over previous
//
#include <hip/hip_runtime.h>

typedef unsigned short u16;
typedef __attribute__((ext_vector_type(8))) short short8;
typedef __attribute__((ext_vector_type(4))) float f32x4;
typedef __attribute__((ext_vector_type(2))) float f32x2;

#define NN 16384   // nodes
#define EE 131072  // edges
#define ERO 32768  // readout edges
#define DF 1024    // appearance dim
#define DL 300     // word2vec dim
#define DLP 320    // K-padded language dim (mult of 32)
#define DLN 384    // N-padded language B^T storage rows (3 tiles of 128)
#define DS 16      // spatial dim
#define NC 117     // classes
#define NCP 128    // padded classes

__device__ __forceinline__ float bf2f(u16 x) {
  unsigned int u = ((unsigned int)x) << 16;
  float f;
  __builtin_memcpy(&f, &u, 4);
  return f;
}
__device__ __forceinline__ u16 f2bf(float f) {
  unsigned int u;
  __builtin_memcpy(&u, &f, 4);
  u = (u + 0x7FFFu + ((u >> 16) & 1u)) >> 16;
  return (u16)u;
}
__device__ __forceinline__ float ld1(const void* p, size_t i, int f) {
  return f ? ((const float*)p)[i] : bf2f(((const u16*)p)[i]);
}
__device__ __forceinline__ void ld4(const void* p, size_t i, int f,
                                    float& x, float& y, float& z, float& w) {
  if (f) {
    float4 v = *(const float4*)((const float*)p + i);
    x = v.x; y = v.y; z = v.z; w = v.w;
  } else {
    ushort4 v = *(const ushort4*)((const u16*)p + i);
    x = bf2f(v.x); y = bf2f(v.y); z = bf2f(v.z); w = bf2f(v.w);
  }
}
__device__ __forceinline__ const void* eoff(const void* p, size_t off, int f) {
  return f ? (const void*)((const float*)p + off) : (const void*)((const u16*)p + off);
}

// dtype probe (measured: f32 on this harness; kept adaptive for safety)
__global__ void detect_kernel(const unsigned int* __restrict__ w, int* __restrict__ flag) {
  unsigned int x = w[threadIdx.x];
  int e = (x >> 7) & 0xFF;
  int ok = (e >= 97 && e <= 157);
  unsigned long long m = __ballot(ok);
  if (threadIdx.x == 0) flag[0] = (__popcll(m) >= 48) ? 0 : 1;  // 0=bf16, 1=f32
}

// contiguous cast to bf16, 8 elems/thread
__global__ void cast_bf16(const int* __restrict__ flag, const void* __restrict__ src,
                          u16* __restrict__ dst, int total8) {
  const int i = blockIdx.x * 256 + threadIdx.x;
  if (i >= total8) return;
  const int fin = flag[0];
  const size_t o = (size_t)i * 8;
  float x0, x1, x2, x3, x4, x5, x6, x7;
  ld4(src, o, fin, x0, x1, x2, x3);
  ld4(src, o + 4, fin, x4, x5, x6, x7);
  ushort4 lo, hi;
  lo.x = f2bf(x0); lo.y = f2bf(x1); lo.z = f2bf(x2); lo.w = f2bf(x3);
  hi.x = f2bf(x4); hi.y = f2bf(x5); hi.z = f2bf(x6); hi.w = f2bf(x7);
  *(ushort4*)(dst + o) = lo;
  *(ushort4*)(dst + o + 4) = hi;
}

// w2v [NN][300] (f32 or bf16) -> bf16 [NN][DLP=320], zero-padded K
__global__ void cast_w2v(const int* __restrict__ flag, const void* __restrict__ src,
                         u16* __restrict__ dst) {
  const int i = blockIdx.x * 256 + threadIdx.x;  // over NN*80 groups of 4
  if (i >= NN * 80) return;
  const int fin = flag[0];
  const int n = i / 80, g = i - n * 80;
  const int c = g << 2;
  ushort4 o;
  if (c < DL) {  // 300 % 4 == 0 -> group fully real or fully pad
    const size_t base = (size_t)n * DL + c;
    o.x = f2bf(ld1(src, base + 0, fin));
    o.y = f2bf(ld1(src, base + 1, fin));
    o.z = f2bf(ld1(src, base + 2, fin));
    o.w = f2bf(ld1(src, base + 3, fin));
  } else {
    o.x = 0; o.y = 0; o.z = 0; o.w = 0;
  }
  *(ushort4*)(dst + (size_t)n * DLP + c) = o;
}

// ---- fused weight prep: 12 transposes in one launch ----
struct TJob2 {
  const void* W; long off;
  u16* out;
  int Kr, Nr, Nstr, Kp, Np, blk0;
};
struct TPack2 { TJob2 j[12]; int nj; };

__global__ void prep_weights2(const int* __restrict__ flag, TPack2 P) {
  int b = blockIdx.x;
  int ji = 0;
  while (ji + 1 < P.nj && b >= P.j[ji + 1].blk0) ++ji;
  const TJob2 J = P.j[ji];
  const int idx = (b - J.blk0) * 256 + threadIdx.x;
  if (idx >= J.Np * J.Kp) return;
  const int n = idx / J.Kp, k = idx % J.Kp;
  float v = 0.f;
  if (k < J.Kr && n < J.Nr) v = ld1(J.W, (size_t)J.off + (size_t)k * J.Nstr + n, flag[0]);
  J.out[idx] = f2bf(v);
}

// ---- legacy 128x128 MFMA GEMM (kept for phase-3 mixed-K job) ----
__device__ __forceinline__ void stage_bf16_async(const u16* __restrict__ G, size_t rbase,
                                                 int lda, int k0, u16* lds, int w, int lane) {
  #pragma unroll
  for (int t = 0; t < 2; ++t) {
    const int rr = (w << 5) + (t << 4) + (lane >> 2);
    const u16* gp = G + (rbase + rr) * (size_t)lda + k0 + ((lane & 3) << 3);
    __builtin_amdgcn_global_load_lds(
        (const __attribute__((address_space(1))) void*)gp,
        (__attribute__((address_space(3))) void*)(lds + (((w << 5) + (t << 4)) * 32)),
        16, 0, 0);
  }
}

__device__ __forceinline__ void stage_f32_manual(const float* __restrict__ G, int row0,
                                                 int lda, int k0, int Kreal,
                                                 u16* lds, int tid) {
  const int r = tid >> 1, half = tid & 1;
  const float* gp = G + (size_t)(row0 + r) * lda + k0 + (half << 4);
  #pragma unroll
  for (int qq = 0; qq < 4; ++qq) {
    const int kk = k0 + (half << 4) + (qq << 2);
    float4 v = make_float4(0.f, 0.f, 0.f, 0.f);
    if (kk < Kreal) v = *(const float4*)(gp + (qq << 2));
    ushort4 o;
    o.x = f2bf(v.x); o.y = f2bf(v.y); o.z = f2bf(v.z); o.w = f2bf(v.w);
    *(ushort4*)(lds + r * 32 + (half << 4) + (qq << 2)) = o;
  }
}

__device__ __forceinline__ void kloop(int am, const void* __restrict__ A, int lda,
                                      int Kreal, int Kpad, const u16* __restrict__ B,
                                      u16* As, u16* Bs, f32x4 (&acc)[4][4],
                                      int row0, int col0,
                                      int tid, int lane, int w, int wm, int wn, int ml, int q) {
  for (int k0 = 0; k0 < Kpad; k0 += 32) {
    if (am == 0) stage_bf16_async((const u16*)A, (size_t)row0, lda, k0, As, w, lane);
    else         stage_f32_manual((const float*)A, row0, lda, k0, Kreal, As, tid);
    stage_bf16_async(B, (size_t)col0, Kpad, k0, Bs, w, lane);
    __syncthreads();
    short8 af[4], bfr[4];
    #pragma unroll
    for (int i = 0; i < 4; ++i)
      af[i] = *(const short8*)(As + ((wm << 6) + (i << 4) + ml) * 32 + (q << 3));
    #pragma unroll
    for (int j = 0; j < 4; ++j)
      bfr[j] = *(const short8*)(Bs + ((wn << 6) + (j << 4) + ml) * 32 + (q << 3));
    #pragma unroll
    for (int i = 0; i < 4; ++i)
      #pragma unroll
      for (int j = 0; j < 4; ++j)
        acc[i][j] = __builtin_amdgcn_mfma_f32_16x16x32_bf16(af[i], bfr[j], acc[i][j], 0, 0, 0);
    __syncthreads();
  }
}

struct GJob {
  const void* A1; const u16* B1;
  const void* A2; const u16* B2;
  const void* bias; void* C;
  int lda1, K1real, K1pad, am1;
  int lda2, K2real, K2pad, am2;   // am2 = -1 -> no second pair
  int inBias, ldc, Nreal, Npad, relu, cf32;
  int gx, gy, blk0;               // tile grid; gy % 8 == 0
};
struct GPack { GJob j[2]; int nj; };

__global__ __launch_bounds__(256) void mfma_jobs(const int* __restrict__ flag, GPack P) {
  const int b = blockIdx.x;
  int ji = 0;
  if (P.nj > 1 && b >= P.j[1].blk0) ji = 1;
  const GJob J = P.j[ji];
  const int t = b - J.blk0;
  const int xcd = t & 7, s = t >> 3;
  const int row_t = xcd * (J.gy >> 3) + s / J.gx;
  const int col_t = s % J.gx;
  const int row0 = row_t << 7;
  const int col0 = col_t << 7;

  __shared__ __attribute__((aligned(16))) u16 As[128 * 32];
  __shared__ __attribute__((aligned(16))) u16 Bs[128 * 32];
  const int tid = threadIdx.x;
  const int lane = tid & 63;
  const int w = tid >> 6;
  const int wm = w >> 1, wn = w & 1;
  const int ml = lane & 15, q = lane >> 4;

  f32x4 acc[4][4];
  #pragma unroll
  for (int i = 0; i < 4; ++i)
    #pragma unroll
    for (int j = 0; j < 4; ++j) {
      f32x4 z = {0.f, 0.f, 0.f, 0.f};
      acc[i][j] = z;
    }

  kloop(J.am1, J.A1, J.lda1, J.K1real, J.K1pad, J.B1, As, Bs, acc,
        row0, col0, tid, lane, w, wm, wn, ml, q);
  if (J.am2 >= 0)
    kloop(J.am2, J.A2, J.lda2, J.K2real, J.K2pad, J.B2, As, Bs, acc,
          row0, col0, tid, lane, w, wm, wn, ml, q);

  const int fin = flag[0];
  // C/D layout (m89-verified): col = lane&15, row = (lane>>4)*4 + reg
  #pragma unroll
  for (int j = 0; j < 4; ++j) {
    const int col = col0 + (wn << 6) + (j << 4) + ml;
    if (col >= J.Npad) continue;
    float bv = 0.f;
    if (J.bias && col < J.Nreal) bv = ld1(J.bias, col, J.inBias ? fin : 0);
    #pragma unroll
    for (int i = 0; i < 4; ++i) {
      #pragma unroll
      for (int r = 0; r < 4; ++r) {
        const int row = row0 + (wm << 6) + (i << 4) + (q << 2) + r;
        float v = 0.f;
        if (col < J.Nreal) {
          v = acc[i][j][r] + bv;
          if (J.relu) v = fmaxf(v, 0.f);
        }
        if (J.cf32) ((float*)J.C)[(size_t)row * J.ldc + col] = v;
        else        ((u16*)J.C)[(size_t)row * J.ldc + col] = f2bf(v);
      }
    }
  }
}

// ======================================================================
// 256x256 8-phase GEMM (T1+T2+T3+T4+T5), bf16 A/B.  (R4-proven)
// Multi-job: per-job grid segment with bijective XCD swizzle (nwg%8==0).
// 8 waves (2M x 4N), BK=64 split in two 32-k halves; LDS 128 KiB 2-dbuf.
// Counted vmcnt(4) at end-P1 / end-P3. Epilogue via per-wave LDS
// transpose -> coalesced ushort8 stores (killed 2.4x write amplification).
// ======================================================================

struct G2Job {
  const u16* A1; const u16* B1;
  const u16* A2; const u16* B2;   // second K-segment (dual-A fused GEMM)
  const void* bias; u16* C;
  int ldk;        // K stride in elements, same for A and B^T
  int nt1, nt2;   // 64-wide K tiles per segment (nt2=0 -> single segment)
  int gx;         // column tiles (N/256)
  int ldc, Nreal, relu, inBias;
  int nwg, blk0;  // grid segment
};
struct G2Pack { G2Job j[2]; int nj; };

#define L2_HALF 16384
#define L2_BUF  65536

__device__ __forceinline__ void barrier_f() {
  asm volatile("" ::: "memory");
  __builtin_amdgcn_s_barrier();
  asm volatile("" ::: "memory");
}

__device__ __forceinline__ void read4f(const char* base, short8 (&dst)[4]) {
  #pragma unroll
  for (int i = 0; i < 4; ++i) dst[i] = *(const short8*)(base + i * 1024);
}

__device__ __forceinline__ void mfma16(f32x4 (&acc)[8][4], const short8 (&af)[4],
                                       const short8 (&bfr)[4], int mg) {
  __builtin_amdgcn_s_setprio(1);
  #pragma unroll
  for (int i = 0; i < 4; ++i)
    #pragma unroll
    for (int n = 0; n < 4; ++n)
      acc[mg * 4 + i][n] =
          __builtin_amdgcn_mfma_f32_16x16x32_bf16(af[i], bfr[n], acc[mg * 4 + i][n], 0, 0, 0);
  __builtin_amdgcn_s_setprio(0);
}

__global__ __launch_bounds__(512, 2) void mfma256(const int* __restrict__ flag, G2Pack P) {
  __shared__ __attribute__((aligned(16))) u16 LDS[65536];  // 128 KiB
  char* ldsc = (char*)LDS;

  const int bid = blockIdx.x;
  const int ji = (P.nj > 1 && bid >= P.j[1].blk0) ? 1 : 0;
  const G2Job J = P.j[ji];
  const int b = bid - J.blk0;
  // T1: bijective XCD swizzle within the job's grid segment (nwg % 8 == 0)
  const int wg = (b & 7) * (J.nwg >> 3) + (b >> 3);
  const int rt = wg / J.gx, ct = wg % J.gx;
  const int row0 = rt << 8, col0 = ct << 8;

  const int tid = threadIdx.x;
  const int lane = tid & 63, w = tid >> 6;
  const int wm = w >> 2, wn = w & 3;
  const int q = lane >> 4, ml = lane & 15;
  const int ldk = J.ldk;
  const int nt = J.nt1 + J.nt2;

  // read-side swizzled in-subtile byte offset (lane-constant)
  const int swzr = (ml * 64 + q * 16) ^ (((ml >> 1) & 3) << 4);
  // stage-side: which (row, col) of the subtile this lane must fetch so
  // that the LINEAR DMA write lands it at its swizzled LDS position
  const int ub = (lane * 16) ^ (((lane >> 3) & 3) << 4);
  const int r_in = ub >> 6, c_in = (ub & 63) >> 1;

  f32x4 acc[8][4];
  #pragma unroll
  for (int m = 0; m < 8; ++m)
    #pragma unroll
    for (int n = 0; n < 4; ++n) { f32x4 z = {0.f, 0.f, 0.f, 0.f}; acc[m][n] = z; }

  // stage one half-tile slice: this wave covers subtiles w*2 and w*2+1
  auto stage = [&](int cb2, const u16* __restrict__ G, int rb, int kc, int boff, int kh) {
    char* lb = ldsc + cb2 * L2_BUF + boff + kh * L2_HALF + w * 2048;
    const u16* g0 = G + (size_t)(rb + w * 32 + r_in) * (size_t)ldk + kc;
    __builtin_amdgcn_global_load_lds((const __attribute__((address_space(1))) void*)g0,
        (__attribute__((address_space(3))) void*)lb, 16, 0, 0);
    const u16* g1 = g0 + (size_t)16 * ldk;
    __builtin_amdgcn_global_load_lds((const __attribute__((address_space(1))) void*)g1,
        (__attribute__((address_space(3))) void*)(lb + 1024), 16, 0, 0);
  };

  // prologue: stage tile 0 (4 half-tiles, 8 loads/thread); release kh0
  stage(0, J.A1, row0, 0 + c_in, 0, 0);
  stage(0, J.B1, col0, 0 + c_in, 32768, 0);
  stage(0, J.A1, row0, 32 + c_in, 0, 1);
  stage(0, J.B1, col0, 32 + c_in, 32768, 1);
  asm volatile("s_waitcnt vmcnt(4)" ::: "memory");
  barrier_f();

  int cb = 0;
  #pragma unroll 1
  for (int kt = 0; kt < nt; ++kt) {
    const int nk = (kt + 1 < nt) ? kt + 1 : kt;  // last tile re-stages itself (dead data)
    const u16* An = (nk < J.nt1) ? J.A1 : J.A2;
    const u16* Bn = (nk < J.nt1) ? J.B1 : J.B2;
    const int kb = ((nk < J.nt1) ? nk : nk - J.nt1) << 6;
    const char* abase = ldsc + cb * L2_BUF + wm * 8192 + swzr;
    const char* bbase = ldsc + cb * L2_BUF + 32768 + wn * 4096 + swzr;
    short8 a0[4], a1[4], bfr[4];

    // ---- P0: kstep 0, m-frags 0-3 ----
    read4f(abase, a0);
    read4f(bbase, bfr);
    stage(cb ^ 1, An, row0, kb + c_in, 0, 0);
    barrier_f();
    mfma16(acc, a0, bfr, 0);
    barrier_f();
    // ---- P1: kstep 0, m-frags 4-7 ----
    read4f(abase + 4096, a1);
    stage(cb ^ 1, Bn, col0, kb + c_in, 32768, 0);
    barrier_f();
    mfma16(acc, a1, bfr, 1);
    asm volatile("s_waitcnt vmcnt(4)" ::: "memory");  // prev-tile kh1 stages landed
    barrier_f();
    // ---- P2: kstep 1, m-frags 0-3 ----
    read4f(abase + L2_HALF, a0);
    read4f(bbase + L2_HALF, bfr);
    stage(cb ^ 1, An, row0, kb + 32 + c_in, 0, 1);
    barrier_f();
    mfma16(acc, a0, bfr, 0);
    barrier_f();
    // ---- P3: kstep 1, m-frags 4-7 ----
    read4f(abase + L2_HALF + 4096, a1);
    stage(cb ^ 1, Bn, col0, kb + 32 + c_in, 32768, 1);
    barrier_f();
    mfma16(acc, a1, bfr, 1);
    asm volatile("s_waitcnt vmcnt(4)" ::: "memory");  // this-tile kh0 stages landed
    barrier_f();
    cb ^= 1;
  }
  // drain outstanding LDS-DMA, then barrier: LDS is dead, reuse for epilogue
  asm volatile("s_waitcnt vmcnt(0)" ::: "memory");
  barrier_f();

  // ---- epilogue: per-wave LDS transpose -> coalesced ushort8 stores ----
  {
    u16* myL = LDS + w * 8192;
    const int fin = flag[0];
    #pragma unroll
    for (int n = 0; n < 4; ++n) {
      const int col_l = n * 16 + ml;
      const int gcol = col0 + wn * 64 + col_l;
      const bool valid = (gcol < J.Nreal);
      float bv = 0.f;
      if (J.bias && valid) bv = ld1(J.bias, gcol, J.inBias ? fin : 0);
      #pragma unroll
      for (int m = 0; m < 8; ++m) {
        #pragma unroll
        for (int r = 0; r < 4; ++r) {
          const int row_l = m * 16 + q * 4 + r;
          float v = 0.f;
          if (valid) {
            v = acc[m][n][r] + bv;
            if (J.relu) v = fmaxf(v, 0.f);
          }
          myL[row_l * 64 + (col_l ^ ((row_l & 7) << 3))] = f2bf(v);
        }
      }
    }
    // read back row-contiguous (wave-private slice; lgkmcnt orders ds ops)
    const int rl0 = lane >> 3, cc = lane & 7;
    #pragma unroll
    for (int t = 0; t < 16; ++t) {
      const int row_l = t * 8 + rl0;
      const short8 vv = *(const short8*)(myL + row_l * 64 + ((cc * 8) ^ ((row_l & 7) << 3)));
      const int grow = row0 + wm * 128 + row_l;
      const int gcol = col0 + wn * 64 + cc * 8;
      if (gcol < J.ldc)
        *(short8*)(&J.C[(size_t)grow * J.ldc + gcol]) = vv;
    }
  }
}

// --- CSR build ---
__global__ void cnt_kernel(const int* __restrict__ edst, int* __restrict__ cnt) {
  const int i = blockIdx.x * 256 + threadIdx.x;
  if (i < EE) atomicAdd(&cnt[edst[i]], 1);
}

__global__ __launch_bounds__(1024) void scan_kernel(const int* __restrict__ cnt,
                                                    int* __restrict__ offs,
                                                    int* __restrict__ woffs) {
  __shared__ int part[1024];
  const int t = threadIdx.x;
  const int base = t * 16;
  int loc[16];
  int s = 0;
  #pragma unroll
  for (int i = 0; i < 16; ++i) { loc[i] = s; s += cnt[base + i]; }
  part[t] = s;
  __syncthreads();
  for (int off = 1; off < 1024; off <<= 1) {
    int v = (t >= off) ? part[t - off] : 0;
    __syncthreads();
    part[t] += v;
    __syncthreads();
  }
  const int chunk_excl = (t == 0) ? 0 : part[t - 1];
  #pragma unroll
  for (int i = 0; i < 16; ++i) {
    int o = chunk_excl + loc[i];
    offs[base + i] = o;
    woffs[base + i] = o;
  }
  if (t == 1023) offs[NN] = part[1023];
}

__global__ void scatter_kernel(const int* __restrict__ esrc, const int* __restrict__ edst,
                               int* __restrict__ woffs,
                               int* __restrict__ order, int* __restrict__ srcs) {
  const int e = blockIdx.x * 256 + threadIdx.x;
  if (e < EE) {
    const int d = edst[e];
    const int pos = atomicAdd(&woffs[d], 1);
    order[pos] = e;
    srcs[pos] = esrc[e];
  }
}

// ======================================================================
// appearance aggregation, f32 fast path (R5-proven pk_fma core), now with
// NODES_PER_BLOCK=8: one weight-slice load (64 KB, ~16 float4/thread)
// amortized over 8 nodes instead of 1. R6 lesson: TLP does the latency
// hiding (2-node ILP interleave REGRESSED, occ 40->29); keep single-node
// inner body, gain by killing the per-block weight preamble (~30% of
// block life) and dispatch overhead (16384 -> 2048 blocks = 8/CU).
// ======================================================================
#define APP_NPB 8

__device__ __forceinline__ void edge4_core(
    const int* __restrict__ ee, const ushort4* __restrict__ pm,
    const float* __restrict__ base, float* __restrict__ a,
    const f32x2 (&w2)[8][4], const float* __restrict__ s_f)
{
  f32x2 u2[4][4];
  #pragma unroll
  for (int m = 0; m < 4; ++m)
    #pragma unroll
    for (int c = 0; c < 4; ++c) u2[m][c] = f32x2{0.f, 0.f};

  f32x2 sA[4][4];
  // k-chunk A: k 0..7
  #pragma unroll
  for (int m = 0; m < 4; ++m) {
    const float4 q0 = *(const float4*)(s_f + (size_t)ee[m] * DS);
    const float4 q1 = *(const float4*)(s_f + (size_t)ee[m] * DS + 4);
    sA[m][0] = f32x2{q0.x, q0.y}; sA[m][1] = f32x2{q0.z, q0.w};
    sA[m][2] = f32x2{q1.x, q1.y}; sA[m][3] = f32x2{q1.z, q1.w};
  }
  #pragma unroll
  for (int h = 0; h < 4; ++h)
    #pragma unroll
    for (int m = 0; m < 4; ++m)
      #pragma unroll
      for (int c = 0; c < 4; ++c)
        u2[m][c] = __builtin_elementwise_fma(sA[m][h], w2[h][c], u2[m][c]);
  // k-chunk B: k 8..15
  #pragma unroll
  for (int m = 0; m < 4; ++m) {
    const float4 q2 = *(const float4*)(s_f + (size_t)ee[m] * DS + 8);
    const float4 q3 = *(const float4*)(s_f + (size_t)ee[m] * DS + 12);
    sA[m][0] = f32x2{q2.x, q2.y}; sA[m][1] = f32x2{q2.z, q2.w};
    sA[m][2] = f32x2{q3.x, q3.y}; sA[m][3] = f32x2{q3.z, q3.w};
  }
  #pragma unroll
  for (int h = 0; h < 4; ++h)
    #pragma unroll
    for (int m = 0; m < 4; ++m)
      #pragma unroll
      for (int c = 0; c < 4; ++c)
        u2[m][c] = __builtin_elementwise_fma(sA[m][h], w2[h + 4][c], u2[m][c]);

  #pragma unroll
  for (int m = 0; m < 4; ++m) {
    a[0] += fmaxf(u2[m][0].x + u2[m][0].y + bf2f(pm[m].x) + base[0], 0.f);
    a[1] += fmaxf(u2[m][1].x + u2[m][1].y + bf2f(pm[m].y) + base[1], 0.f);
    a[2] += fmaxf(u2[m][2].x + u2[m][2].y + bf2f(pm[m].z) + base[2], 0.f);
    a[3] += fmaxf(u2[m][3].x + u2[m][3].y + bf2f(pm[m].w) + base[3], 0.f);
  }
}

__device__ __forceinline__ void edge1_core(
    int e, const ushort4 p1, const float* __restrict__ base, float* __restrict__ a,
    const f32x2 (&w2)[8][4], const float* __restrict__ s_f)
{
  f32x2 u2[4] = {f32x2{0.f, 0.f}, f32x2{0.f, 0.f}, f32x2{0.f, 0.f}, f32x2{0.f, 0.f}};
  #pragma unroll
  for (int h4 = 0; h4 < 4; ++h4) {
    const float4 qq = *(const float4*)(s_f + (size_t)e * DS + h4 * 4);
    const f32x2 s0 = f32x2{qq.x, qq.y}, s1 = f32x2{qq.z, qq.w};
    #pragma unroll
    for (int c = 0; c < 4; ++c) {
      u2[c] = __builtin_elementwise_fma(s0, w2[h4 * 2][c], u2[c]);
      u2[c] = __builtin_elementwise_fma(s1, w2[h4 * 2 + 1][c], u2[c]);
    }
  }
  a[0] += fmaxf(u2[0].x + u2[0].y + bf2f(p1.x) + base[0], 0.f);
  a[1] += fmaxf(u2[1].x + u2[1].y + bf2f(p1.y) + base[1], 0.f);
  a[2] += fmaxf(u2[2].x + u2[2].y + bf2f(p1.z) + base[2], 0.f);
  a[3] += fmaxf(u2[3].x + u2[3].y + bf2f(p1.w) + base[3], 0.f);
}

__device__ __forceinline__ void app_agg_f32(
    const u16* __restrict__ P12, const float* __restrict__ s_f,
    const float* __restrict__ W_es, const float* __restrict__ b_e,
    const int* __restrict__ offs, const int* __restrict__ order,
    const int* __restrict__ srcs, u16* __restrict__ aggn)
{
  const int tid = threadIdx.x;
  const int c4 = tid << 2;

  // weight pairs across k, loaded ONCE per block: w2[h][c] = {W[2h][c4+c], W[2h+1][c4+c]}
  f32x2 w2[8][4];
  #pragma unroll
  for (int h = 0; h < 8; ++h) {
    const float4 r0 = *(const float4*)(W_es + (size_t)(2 * h) * DF + c4);
    const float4 r1 = *(const float4*)(W_es + (size_t)(2 * h + 1) * DF + c4);
    w2[h][0] = f32x2{r0.x, r1.x}; w2[h][1] = f32x2{r0.y, r1.y};
    w2[h][2] = f32x2{r0.z, r1.z}; w2[h][3] = f32x2{r0.w, r1.w};
  }
  const float4 be = *(const float4*)(b_e + c4);

  const int n0 = blockIdx.x * APP_NPB;
  #pragma unroll 1
  for (int n = n0; n < n0 + APP_NPB; ++n) {
    const ushort4 p2 = *(const ushort4*)(P12 + ((size_t)(unsigned)(n << 11)) + 1024 + c4);
    float base[4];
    base[0] = bf2f(p2.x) + be.x; base[1] = bf2f(p2.y) + be.y;
    base[2] = bf2f(p2.z) + be.z; base[3] = bf2f(p2.w) + be.w;

    const int beg = offs[n], end = offs[n + 1];
    float a[4] = {0.f, 0.f, 0.f, 0.f};
    int j = beg;
    for (; j + 4 <= end; j += 4) {
      int ee[4];
      ushort4 pm[4];
      #pragma unroll
      for (int m = 0; m < 4; ++m) {
        ee[m] = order[j + m];
        pm[m] = *(const ushort4*)(P12 + ((size_t)(unsigned)(srcs[j + m] << 11)) + c4);
      }
      edge4_core(ee, pm, base, a, w2, s_f);
    }
    for (; j < end; ++j) {
      const ushort4 p1 = *(const ushort4*)(P12 + ((size_t)(unsigned)(srcs[j] << 11)) + c4);
      edge1_core(order[j], p1, base, a, w2, s_f);
    }
    const float inv = 1.f / fmaxf((float)(end - beg), 1.f);
    ushort4 o;
    o.x = f2bf(a[0] * inv); o.y = f2bf(a[1] * inv);
    o.z = f2bf(a[2] * inv); o.w = f2bf(a[3] * inv);
    *(ushort4*)(aggn + (size_t)n * DF + c4) = o;
  }
}

// bf16-input fallback (generic scalar path, correctness-only), 8 nodes/block
__device__ __forceinline__ void app_agg_bf16(
    const u16* __restrict__ P12, const void* __restrict__ s_f,
    const void* __restrict__ W_eb, const void* __restrict__ b_e,
    const int* __restrict__ offs, const int* __restrict__ order,
    const int* __restrict__ srcs, u16* __restrict__ aggn)
{
  const int tid = threadIdx.x;
  const int c4 = tid << 2;
  const void* W_es = eoff(W_eb, (size_t)2 * DF * DF, 0);

  float wx[16], wy[16], wz[16], ww[16];
  #pragma unroll
  for (int k = 0; k < 16; ++k)
    ld4(W_es, (size_t)k * DF + c4, 0, wx[k], wy[k], wz[k], ww[k]);

  float be0, be1, be2, be3;
  ld4(b_e, c4, 0, be0, be1, be2, be3);

  const int n0 = blockIdx.x * APP_NPB;
  #pragma unroll 1
  for (int n = n0; n < n0 + APP_NPB; ++n) {
    const ushort4 p2 = *(const ushort4*)(P12 + ((size_t)(unsigned)(n << 11)) + 1024 + c4);
    const float base0 = bf2f(p2.x) + be0;
    const float base1 = bf2f(p2.y) + be1;
    const float base2 = bf2f(p2.z) + be2;
    const float base3 = bf2f(p2.w) + be3;

    const int beg = offs[n], end = offs[n + 1];
    float a0 = 0.f, a1 = 0.f, a2 = 0.f, a3 = 0.f;
    for (int j = beg; j < end; ++j) {
      const int e = order[j], s = srcs[j];
      float sf[16];
      #pragma unroll
      for (int k = 0; k < 16; k += 4)
        ld4(s_f, (size_t)e * DS + k, 0, sf[k], sf[k + 1], sf[k + 2], sf[k + 3]);
      const ushort4 p1 = *(const ushort4*)(P12 + ((size_t)(unsigned)(s << 11)) + c4);
      float v0 = bf2f(p1.x) + base0;
      float v1 = bf2f(p1.y) + base1;
      float v2 = bf2f(p1.z) + base2;
      float v3 = bf2f(p1.w) + base3;
      #pragma unroll
      for (int k = 0; k < 16; ++k) {
        v0 = fmaf(sf[k], wx[k], v0);
        v1 = fmaf(sf[k], wy[k], v1);
        v2 = fmaf(sf[k], wz[k], v2);
        v3 = fmaf(sf[k], ww[k], v3);
      }
      a0 += fmaxf(v0, 0.f); a1 += fmaxf(v1, 0.f);
      a2 += fmaxf(v2, 0.f); a3 += fmaxf(v3, 0.f);
    }
    const float inv = 1.f / fmaxf((float)(end - beg), 1.f);
    ushort4 o;
    o.x = f2bf(a0 * inv); o.y = f2bf(a1 * inv);
    o.z = f2bf(a2 * inv); o.w = f2bf(a3 * inv);
    *(ushort4*)(aggn + (size_t)n * DF + c4) = o;
  }
}

__global__ __launch_bounds__(256) void app_agg(
    const int* __restrict__ flag,
    const u16* __restrict__ P12, const void* __restrict__ s_f,
    const void* __restrict__ W_eb, const void* __restrict__ b_e,
    const int* __restrict__ offs, const int* __restrict__ order,
    const int* __restrict__ srcs, u16* __restrict__ aggn)
{
  if (flag[0])
    app_agg_f32(P12, (const float*)s_f, (const float*)W_eb + (size_t)2 * DF * DF,
                (const float*)b_e, offs, order, srcs, aggn);
  else
    app_agg_bf16(P12, s_f, W_eb, b_e, offs, order, srcs, aggn);
}

// language aggregation, vectorized: 8 nodes/block x 40 threads x ushort8.
// Q12 interleaved [n][768] (Q1 @0 | Q2 @384); out [NN][DLP] zero-pad.
__global__ __launch_bounds__(320) void lang_agg(
    const int* __restrict__ flag,
    const u16* __restrict__ Q12, const void* __restrict__ b_el,
    const int* __restrict__ offs, const int* __restrict__ srcs,
    u16* __restrict__ aggln)
{
  const int fin = flag[0];
  const int tid = threadIdx.x;
  const int g = tid / 40;            // local node 0..7
  const int c8 = (tid - g * 40) * 8; // 0..312
  const int n = blockIdx.x * 8 + g;

  // base[i] = Q2[n][c8+i] + b_el[c8+i]; pad cols (>=300) have Q2=0, b_el=0
  const short8 q2 = *(const short8*)(Q12 + (size_t)n * 768 + 384 + c8);
  float base[8];
  #pragma unroll
  for (int i = 0; i < 8; ++i)
    base[i] = bf2f((u16)q2[i]) + ((c8 + i < DL) ? ld1(b_el, c8 + i, fin) : 0.f);

  const int beg = offs[n], end = offs[n + 1];
  float s0[8] = {0, 0, 0, 0, 0, 0, 0, 0}, s1[8] = {0, 0, 0, 0, 0, 0, 0, 0};
  int j = beg;
  for (; j + 2 <= end; j += 2) {
    const int sa = srcs[j], sb = srcs[j + 1];
    const short8 va = *(const short8*)(Q12 + (size_t)sa * 768 + c8);
    const short8 vb = *(const short8*)(Q12 + (size_t)sb * 768 + c8);
    #pragma unroll
    for (int i = 0; i < 8; ++i) {
      s0[i] += fmaxf(bf2f((u16)va[i]) + base[i], 0.f);
      s1[i] += fmaxf(bf2f((u16)vb[i]) + base[i], 0.f);
    }
  }
  if (j < end) {
    const int sa = srcs[j];
    const short8 va = *(const short8*)(Q12 + (size_t)sa * 768 + c8);
    #pragma unroll
    for (int i = 0; i < 8; ++i) s0[i] += fmaxf(bf2f((u16)va[i]) + base[i], 0.f);
  }
  const float inv = 1.f / fmaxf((float)(end - beg), 1.f);
  short8 o;
  #pragma unroll
  for (int i = 0; i < 8; ++i) o[i] = (short)f2bf((s0[i] + s1[i]) * inv);
  *(short8*)(aggln + (size_t)n * DLP + c8) = o;
}

// pred[e] = RdRs[dst,0:117] + RdRs[src,128:245] + s_f_ro[e]@Wp_s + b_p
__global__ __launch_bounds__(256) void readout_kernel(
    const int* __restrict__ flag,
    const float* __restrict__ RdRs,
    const void* __restrict__ s_f_ro,
    const void* __restrict__ W_pb, size_t offWps,
    const void* __restrict__ b_p,
    const int* __restrict__ rsrc, const int* __restrict__ rdst, void* __restrict__ out)
{
  const int fin = flag[0];
  __shared__ float wps[16 * NC];
  const void* Wp_s = eoff(W_pb, offWps, fin);
  const int tid = threadIdx.x;
  for (int i = tid; i < 16 * NC; i += 256) wps[i] = ld1(Wp_s, i, fin);
  __syncthreads();
  const int slot = tid >> 7;        // 0 or 1
  const int c = tid & 127;
  const float bp = (c < NC) ? ld1(b_p, c, fin) : 0.f;

  const int e0 = (blockIdx.x << 3) + slot;
  #pragma unroll
  for (int ee = 0; ee < 8; ee += 2) {
    const int e = e0 + ee;
    const int s = rsrc[e];
    const int d = rdst[e];
    if (c < NC) {
      float acc = RdRs[(size_t)d * 256 + c] + RdRs[(size_t)s * 256 + 128 + c] + bp;
      #pragma unroll
      for (int k = 0; k < 16; ++k)
        acc = fmaf(ld1(s_f_ro, (size_t)e * DS + k, fin), wps[k * NC + c], acc);
      if (fin) ((float*)out)[(size_t)e * NC + c] = acc;
      else     ((u16*)out)[(size_t)e * NC + c] = f2bf(acc);
    }
  }
}

extern "C" void kernel_launch(void* const* d_in, const int* in_sizes, int n_in,
                              void* d_out, int out_size, void* d_ws, size_t ws_size,
                              hipStream_t stream)
{
  const void* feat  = d_in[0];
  const void* w2v   = d_in[1];
  const void* s_f   = d_in[2];
  const void* s_fro = d_in[3];
  const void* W_e   = d_in[4];
  const void* b_e   = d_in[5];
  const void* W_el  = d_in[6];
  const void* b_el  = d_in[7];
  const void* W_nu  = d_in[8];
  const void* b_nu  = d_in[9];
  const void* W_nul = d_in[10];
  const void* b_nul = d_in[11];
  const void* W_p   = d_in[12];
  const void* b_p   = d_in[13];
  const int* esrc  = (const int*)d_in[14];
  const int* edst  = (const int*)d_in[15];
  const int* rsrc  = (const int*)d_in[16];
  const int* rdst  = (const int*)d_in[17];

  // ---- workspace layout: ~183 MB ----
  char* p = (char*)d_ws;
  int* flag  = (int*)p; p += 256;
  int* cnt   = (int*)p; p += (size_t)NN * 4;
  int* offs  = (int*)p; p += (size_t)(NN + 64) * 4;
  int* woffs = (int*)p; p += (size_t)NN * 4;
  int* order = (int*)p; p += (size_t)EE * 4;
  int* srcs  = (int*)p; p += (size_t)EE * 4;
  u16* featB  = (u16*)p; p += (size_t)NN * DF * 2;        // 32 MB bf16 feat
  u16* We12T  = (u16*)p; p += (size_t)2 * DF * DF * 2;    // [2048][1024]
  u16* Wnu1T  = (u16*)p; p += (size_t)DF * DF * 2;
  u16* Wnu2T  = (u16*)p; p += (size_t)DF * DF * 2;
  u16* Wel12T = (u16*)p; p += (size_t)2 * DLN * DLP * 2;  // [768][320]
  u16* Wnul1T = (u16*)p; p += (size_t)DLN * DLP * 2;
  u16* Wnul2T = (u16*)p; p += (size_t)DLN * DLP * 2;
  u16* WpFT2  = (u16*)p; p += (size_t)2 * NCP * DF * 2;   // [256][1024] (Rd-F | Rs-F)
  u16* WpLT2  = (u16*)p; p += (size_t)2 * NCP * DLP * 2;  // [256][320]  (Rd-L | Rs-L)
  u16* P12   = (u16*)p; p += (size_t)NN * 2048 * 2;       // 64 MB; later newf+newl
  u16* Q12   = (u16*)p; p += (size_t)NN * 768 * 2;        // 24 MB; later RdRs (16 MB f32)
  u16* aggln = (u16*)p; p += (size_t)NN * DLP * 2;        // 10 MB
  u16* aggn  = (u16*)p; p += (size_t)NN * DF * 2;         // 32 MB
  u16* w2vB  = (u16*)p; p += (size_t)NN * DLP * 2;        // 10.5 MB bf16 K-padded w2v
  // aliases (stream-ordered: P12 dead after app_agg; Q12 dead after lang_agg)
  u16* newf = P12;
  u16* newl = P12 + (size_t)NN * DF;
  float* RdRs = (float*)Q12;

  detect_kernel<<<1, 64, 0, stream>>>((const unsigned int*)feat, flag);
  hipMemsetAsync(cnt, 0, (size_t)NN * 4, stream);
  cast_bf16<<<(NN * DF / 8 + 255) / 256, 256, 0, stream>>>(flag, feat, featB, NN * DF / 8);
  cast_w2v<<<(NN * 80 + 255) / 256, 256, 0, stream>>>(flag, w2v, w2vB);

  // ---- fused weight prep (12 transposes, one launch) ----
  TPack2 tp{};
  int tb = 0, tn = 0;
  auto T = [&](const void* W, long off, int Kr, int Nr, int Nstr, u16* out, int Kp, int Np) {
    tp.j[tn] = TJob2{W, off, out, Kr, Nr, Nstr, Kp, Np, tb};
    tb += (Np * Kp + 255) / 256;
    ++tn;
  };
  T(W_e,   0,                   DF, DF, DF, We12T,                     DF, DF);
  T(W_e,   (long)DF * DF,       DF, DF, DF, We12T + (size_t)DF * DF,   DF, DF);
  T(W_nu,  0,                   DF, DF, DF, Wnu1T, DF, DF);
  T(W_nu,  (long)DF * DF,       DF, DF, DF, Wnu2T, DF, DF);
  T(W_el,  0,                   DL, DL, DL, Wel12T,                     DLP, DLN);
  T(W_el,  (long)DL * DL,       DL, DL, DL, Wel12T + (size_t)DLN * DLP, DLP, DLN);
  T(W_nul, 0,                   DL, DL, DL, Wnul1T, DLP, DLN);
  T(W_nul, (long)DL * DL,       DL, DL, DL, Wnul2T, DLP, DLN);
  T(W_p,   0,                                DF, NC, NC, WpFT2,                     DF,  NCP);
  T(W_p,   (long)(DF + DL + DS + DL) * NC,   DF, NC, NC, WpFT2 + (size_t)NCP * DF,  DF,  NCP);
  T(W_p,   (long)DF * NC,                    DL, NC, NC, WpLT2,                     DLP, NCP);
  T(W_p,   (long)(DF + DL + DS) * NC,        DL, NC, NC, WpLT2 + (size_t)NCP * DLP, DLP, NCP);
  tp.nj = tn;
  prep_weights2<<<tb, 256, 0, stream>>>(flag, tp);

  // ---- CSR build ----
  cnt_kernel<<<EE / 256, 256, 0, stream>>>(edst, cnt);
  scan_kernel<<<1, 1024, 0, stream>>>(cnt, offs, woffs);
  scatter_kernel<<<EE / 256, 256, 0, stream>>>(esrc, edst, woffs, order, srcs);

  // ---- GEMM phase 1 (one launch, 2 jobs): P12 = featB @ We12T^T  |  Q12 = w2vB @ Wel12T^T
  {
    G2Pack g{};
    g.j[0] = G2Job{featB, We12T, nullptr, nullptr, nullptr, P12,
                   DF, 16, 0, 8, 2048, 2048, 0, 0, 512, 0};
    g.j[1] = G2Job{w2vB, Wel12T, nullptr, nullptr, nullptr, Q12,
                   DLP, 5, 0, 3, 768, 768, 0, 0, 192, 512};
    g.nj = 2;
    mfma256<<<704, 512, 0, stream>>>(flag, g);
  }

  // ---- aggregations (CSR, no atomics) ----
  lang_agg<<<NN / 8, 320, 0, stream>>>(flag, Q12, b_el, offs, srcs, aggln);
  app_agg<<<NN / APP_NPB, 256, 0, stream>>>(flag, P12, s_f, W_e, b_e, offs, order, srcs, aggn);

  // ---- GEMM phase 2 (one launch, 2 jobs): node updates (newf/newl alias P12) ----
  {
    G2Pack g{};
    g.j[0] = G2Job{featB, Wnu1T, aggn, Wnu2T, b_nu, newf,
                   DF, 16, 16, 4, DF, DF, 1, 1, 256, 0};
    g.j[1] = G2Job{w2vB, Wnul1T, aggln, Wnul2T, b_nul, newl,
                   DLP, 5, 5, 2, DLP, DL, 1, 1, 128, 256};
    g.nj = 2;
    mfma256<<<384, 512, 0, stream>>>(flag, g);
  }

  // ---- GEMM phase 3: fused readout projections (f32, [NN][256]: Rd | Rs) ----
  {
    GPack g{};
    g.j[0] = GJob{newf, WpFT2, newl, WpLT2, nullptr, RdRs,
                  DF, DF, DF, 0,    DLP, DLP, DLP, 0,
                  0, 256, 256, 256, 0, 1,    2, 128, 0};
    g.nj = 1;
    mfma_jobs<<<256, 256, 0, stream>>>(flag, g);
  }

  readout_kernel<<<ERO / 8, 256, 0, stream>>>(flag, RdRs, s_fro,
                                              W_p, (size_t)(DF + DL) * NC, b_p,
                                              rsrc, rdst, d_out);
}